// Round 11
// baseline (480.100 us; speedup 1.0000x reference)
//
#include <hip/hip_runtime.h>
#include <math.h>

// OLE loss on MI355X — SINGLE dispatch.
// ||X_c||* = trace(sqrt(G_c)), G_c = X_c^T X_c (128x128).
// Blocks 0..63: gram(c) in registers -> write G_c+flag -> NS on own class.
// Blocks 65..191: CE; 65..80 also wait gram flags -> Gall slices -> flag.
// Block 64: wait Gall flags -> NS on Gall -> wait nuc/CE flags -> combine.
// Flags are MAGIC-value (no memset needed; ws poison 0xAA resets them).
// NS: Y,M split bf16 hi/lo, Z single bf16, Frobenius norm, scaled ladder
// (9 iters), trace anchored on fp32 G.  (R8 lesson: no grid.sync — ~50us
// per barrier across 8 XCDs.  R10 lesson: release/acquire AGENT flags work.)

#define N_ROWS 8192
#define DIM    128
#define NCLS   64
#define NMAT   65
#define NITER  9
#define EPSN   2e-4f
#define LAMBDA_ 0.25f
#define DELTA_  1.0f
#define MAGIC  0x13579BDF
#define NCEB   127          // CE blocks: 65..191
#define NCEW   (NCEB * 8)   // 1016 CE waves

typedef __attribute__((ext_vector_type(8))) short s16x8;  // 8 bf16 = 4 VGPR
typedef __attribute__((ext_vector_type(4))) short s16x4;  // 4 bf16
typedef __attribute__((ext_vector_type(4))) float f32x4;

// Scaled-NS ladder: M_k = C1[k]*I - C2[k]*W, C1 = 1.5*sqrt(t), C2 = 0.5*t^1.5.
// t = [2.9, 2.758, 2.13, 1.868, 1.264, 1,1,1,1]; u = t*w, w' = u(1.5-u/2)^2
// stays in (0,1] for u in (0,3) -> sign-safe; final t=1 steps polish w->1.
static __device__ const float NS_C1[NITER] =
  {2.554408f, 2.491084f, 2.189178f, 2.050122f, 1.686417f, 1.5f, 1.5f, 1.5f, 1.5f};
static __device__ const float NS_C2[NITER] =
  {2.469261f, 2.290137f, 1.554316f, 1.276543f, 0.710544f, 0.5f, 0.5f, 0.5f, 0.5f};

__device__ __forceinline__ unsigned short f2bf(float f) {   // RNE
  unsigned u = __float_as_uint(f);
  u = (u + 0x7FFFu + ((u >> 16) & 1u)) >> 16;
  return (unsigned short)u;
}
__device__ __forceinline__ float bf2f(unsigned short h) {
  return __uint_as_float(((unsigned)h) << 16);
}

// bf16 LDS: element (i,j) at short-index i*128 + (((j>>3)^(i&15))<<3) + (j&7)
__device__ __forceinline__ int swz_idx(int i, int j) {
  return i * 128 + (((j >> 3) ^ (i & 15)) << 3) + (j & 7);
}

__device__ __forceinline__ s16x8 load_frag(const short* buf, int row0,
                                           int kstep, int lane) {
  int m  = row0 + (lane & 15);
  int kg = kstep * 4 + (lane >> 4);
  return *(const s16x8*)(buf + m * 128 + ((kg ^ (m & 15)) << 3));
}

__device__ __forceinline__ void flag_set(int* p) {
  __threadfence();
  __hip_atomic_store(p, MAGIC, __ATOMIC_RELEASE, __HIP_MEMORY_SCOPE_AGENT);
}
__device__ __forceinline__ void flag_wait(const int* p) {
  while (__hip_atomic_load(p, __ATOMIC_ACQUIRE, __HIP_MEMORY_SCOPE_AGENT) != MAGIC)
    __builtin_amdgcn_s_sleep(16);
}

// ---------------------------------------------------------------------------
__global__ __launch_bounds__(512, 1) void ole_mono(const float* __restrict__ feat,
                                                   const int* __restrict__ y,
                                                   const float* __restrict__ logits,
                                                   float* __restrict__ G,
                                                   float* __restrict__ nuc,
                                                   float* __restrict__ cepart,
                                                   int* __restrict__ gflag,
                                                   int* __restrict__ gallf,
                                                   int* __restrict__ nflag,
                                                   int* __restrict__ cflag,
                                                   float* __restrict__ out) {
  __shared__ __align__(16) short smem[5 * DIM * DIM];   // 160 KiB exactly
  short* Yh = smem;
  short* Yl = smem + DIM * DIM;
  short* Mh = smem + 2 * DIM * DIM;
  short* Ml = smem + 3 * DIM * DIM;
  short* Zb = smem + 4 * DIM * DIM;

  const int bid  = blockIdx.x;
  const int tid  = threadIdx.x;
  const int lane = tid & 63;
  const int quad = lane >> 4;
  const int wv   = tid >> 6;    // 0..7

  // ======================= CE blocks (65..191) ==========================
  if (bid > NCLS) {
    const int blk   = bid - NMAT;          // 0..126
    const int gwave = blk * 8 + wv;        // 0..1015

    float acc_ce = 0.f;
    for (int row = gwave; row < N_ROWS; row += NCEW) {
      float v = logits[row * NCLS + lane];
      float mx = v;
      for (int off = 32; off > 0; off >>= 1) mx = fmaxf(mx, __shfl_xor(mx, off, 64));
      float e = expf(v - mx);
      for (int off = 32; off > 0; off >>= 1) e += __shfl_xor(e, off, 64);
      if (lane == 0) {
        int t = y[row];
        acc_ce += (mx + logf(e)) - logits[row * NCLS + t];
      }
    }
    if (lane == 0) cepart[gwave] = acc_ce;
    __syncthreads();
    if (tid == 0) flag_set(&cflag[blk]);

    if (blk < 16) {                        // Gall duty
      if (tid == 0)
        for (int c = 0; c < NCLS; ++c) flag_wait(&gflag[c]);
      __syncthreads();
      if (tid < 256) {
        int idx4 = blk * 256 + tid;        // 16 blocks x 256 = 4096 float4s
        const float4* G4 = (const float4*)G;
        float4 s = make_float4(0.f, 0.f, 0.f, 0.f);
#pragma unroll 8
        for (int c = 0; c < NCLS; ++c) {
          float4 v = G4[(size_t)c * (DIM * DIM / 4) + idx4];
          s.x += v.x; s.y += v.y; s.z += v.z; s.w += v.w;
        }
        ((float4*)G)[(size_t)NCLS * (DIM * DIM / 4) + idx4] = s;
      }
      __syncthreads();
      if (tid == 0) flag_set(&gallf[blk]);
    }
    return;
  }

  // ======================= NS blocks (0..64) ============================
  // garr[32]: this thread's 32 fp32 G elements.
  //  bid<64 (gram layout): garr[a*4+e] = G(i0+a, j0g+e)
  //  bid==64 (loader layout): garr[t*4+e] = G(flat/128, flat%128+e), flat=4*(tid+512t)
  float garr[32];
  const int ti = tid >> 5, tj = tid & 31;
  const int i0 = ti * 8,  j0g = tj * 4;
  float tpart = 0.f, fpart = 0.f;

  if (bid < NCLS) {
    // ---------------- gram phase (512 threads, 8x4 tile) ----------------
    int*  list = (int*)smem;               // 32 KB (= Yh region)
    int*  cntp = list + 8192;
    float (*xs)[DIM] = (float (*)[DIM])(list + 8196);   // 8 KB, in Yl region

    const int c = bid;
    if (tid == 0) *cntp = 0;
    __syncthreads();
    const int4* y4 = (const int4*)y;
#pragma unroll
    for (int t = 0; t < 4; ++t) {
      int g4 = tid + 512 * t;
      int4 v = y4[g4];
      int r0 = g4 * 4;
      if (v.x == c) list[atomicAdd(cntp, 1)] = r0;
      if (v.y == c) list[atomicAdd(cntp, 1)] = r0 + 1;
      if (v.z == c) list[atomicAdd(cntp, 1)] = r0 + 2;
      if (v.w == c) list[atomicAdd(cntp, 1)] = r0 + 3;
    }
    __syncthreads();
    const int n = *cntp;

#pragma unroll
    for (int k = 0; k < 32; ++k) garr[k] = 0.f;

    for (int base = 0; base < n; base += 16) {
      __syncthreads();
      int li = base + (tid >> 5);
      float4 v = make_float4(0.f, 0.f, 0.f, 0.f);
      if (li < n) v = *(const float4*)(feat + (size_t)list[li] * DIM + (tid & 31) * 4);
      *(float4*)(&xs[tid >> 5][(tid & 31) * 4]) = v;
      __syncthreads();
#pragma unroll
      for (int rw = 0; rw < 16; ++rw) {
        float xi[8], xj[4];
#pragma unroll
        for (int a = 0; a < 8; ++a) xi[a] = xs[rw][i0 + a];
#pragma unroll
        for (int b = 0; b < 4; ++b) xj[b] = xs[rw][j0g + b];
#pragma unroll
        for (int a = 0; a < 8; ++a)
#pragma unroll
          for (int b = 0; b < 4; ++b)
            garr[a * 4 + b] = fmaf(xi[a], xj[b], garr[a * 4 + b]);
      }
    }

    // write G_c for the Gall builders, then signal
    float* Gc = G + (size_t)c * DIM * DIM;
#pragma unroll
    for (int a = 0; a < 8; ++a)
      *(float4*)(Gc + (i0 + a) * DIM + j0g) = *(float4*)(&garr[a * 4]);
    __syncthreads();
    if (tid == 0) flag_set(&gflag[c]);

    // trace / fro2 partials from registers
#pragma unroll
    for (int a = 0; a < 8; ++a)
#pragma unroll
      for (int e = 0; e < 4; ++e) {
        float g = garr[a * 4 + e];
        fpart += g * g;
        if (i0 + a == j0g + e) tpart += g;
      }
  } else {
    // ---------------- block 64: wait for Gall, load it ------------------
    if (tid == 0)
      for (int b = 0; b < 16; ++b) flag_wait(&gallf[b]);
    __syncthreads();
    const float4* Gm4 = (const float4*)(G + (size_t)NCLS * DIM * DIM);
#pragma unroll
    for (int t = 0; t < 8; ++t) {
      int idx4 = tid + 512 * t;
      float4 v = Gm4[idx4];
      *(float4*)(&garr[t * 4]) = v;
      fpart += v.x * v.x + v.y * v.y + v.z * v.z + v.w * v.w;
      int flat = idx4 * 4, i = flat >> 7, j0 = flat & 127;
      if (j0 <= i && i < j0 + 4) tpart += garr[t * 4 + (i - j0)];
    }
  }

  // ---- block stats reduction (redf lives in Zb; untouched so far) ----
  for (int off = 32; off > 0; off >>= 1) {
    tpart += __shfl_down(tpart, off, 64);
    fpart += __shfl_down(fpart, off, 64);
  }
  __syncthreads();                    // gram xs/list reads all done
  float* redf = (float*)Zb;
  if (lane == 0) { redf[wv] = tpart; redf[8 + wv] = fpart; }
  __syncthreads();
  float trace = 0.f, fro2 = 0.f;
#pragma unroll
  for (int w = 0; w < 8; ++w) { trace += redf[w]; fro2 += redf[8 + w]; }
  __syncthreads();                    // redf reads done -> Zb reusable

  float s = sqrtf(fro2);
  if (s < 1e-12f) s = 1.f;
  const float invs = 1.f / s;
  const float eps  = EPSN * trace * invs;

  // ---- init: Y0 = G/s + eps*I (hi/lo), Z0 = I ----
  if (bid < NCLS) {
#pragma unroll
    for (int a = 0; a < 8; ++a) {
      int i = i0 + a;
      s16x4 vh, vl;
#pragma unroll
      for (int e = 0; e < 4; ++e) {
        float x = garr[a * 4 + e] * invs + ((i == j0g + e) ? eps : 0.f);
        unsigned short hh = f2bf(x);
        vh[e] = (short)hh;
        vl[e] = (short)f2bf(x - bf2f(hh));
      }
      int idx = swz_idx(i, j0g);
      *(s16x4*)(Yh + idx) = vh;
      *(s16x4*)(Yl + idx) = vl;
    }
  } else {
#pragma unroll
    for (int t = 0; t < 8; ++t) {
      int idx4 = tid + 512 * t;
      int flat = idx4 * 4, i = flat >> 7, j0 = flat & 127;
      s16x4 vh, vl;
#pragma unroll
      for (int e = 0; e < 4; ++e) {
        float x = garr[t * 4 + e] * invs + ((i == j0 + e) ? eps : 0.f);
        unsigned short hh = f2bf(x);
        vh[e] = (short)hh;
        vl[e] = (short)f2bf(x - bf2f(hh));
      }
      int idx = swz_idx(i, j0);
      *(s16x4*)(Yh + idx) = vh;
      *(s16x4*)(Yl + idx) = vl;
    }
  }
  for (int grp = tid; grp < DIM * 16; grp += 512) {
    int i = grp >> 4, g = grp & 15;
    s16x8 v = (s16x8)0;
    if ((i >> 3) == g) v[i & 7] = (short)0x3F80;   // 1.0 bf16
    *(s16x8*)(Zb + i * 128 + ((g ^ (i & 15)) << 3)) = v;
  }
  __syncthreads();

  const int wr = wv >> 2;     // 0..1 -> tile-rows 4*wr..4*wr+3
  const int wc = wv & 3;      // 0..3 -> tile-cols 2*wc..2*wc+1

  for (int it = 0; it < NITER; ++it) {
    const float kA = NS_C1[it];
    const float kB = NS_C2[it];

    // --- (a) W = Z*Y (Yh+Yl) ---
    f32x4 acc[4][2];
#pragma unroll
    for (int r = 0; r < 4; ++r)
#pragma unroll
      for (int c2 = 0; c2 < 2; ++c2) acc[r][c2] = (f32x4)0.f;
#pragma unroll
    for (int ks = 0; ks < 4; ++ks) {
      s16x8 a[4], bh[2], bl[2];
#pragma unroll
      for (int r = 0; r < 4; ++r) a[r] = load_frag(Zb, (4 * wr + r) * 16, ks, lane);
#pragma unroll
      for (int c2 = 0; c2 < 2; ++c2) {
        bh[c2] = load_frag(Yh, (2 * wc + c2) * 16, ks, lane);
        bl[c2] = load_frag(Yl, (2 * wc + c2) * 16, ks, lane);
      }
#pragma unroll
      for (int r = 0; r < 4; ++r)
#pragma unroll
        for (int c2 = 0; c2 < 2; ++c2) {
          acc[r][c2] = __builtin_amdgcn_mfma_f32_16x16x32_bf16(a[r], bh[c2], acc[r][c2], 0, 0, 0);
          acc[r][c2] = __builtin_amdgcn_mfma_f32_16x16x32_bf16(a[r], bl[c2], acc[r][c2], 0, 0, 0);
        }
    }
    // --- (b) M = kA*I - kB*W, clamp, hi/lo split, transposed store ---
#pragma unroll
    for (int r = 0; r < 4; ++r) {
      int ibase = (4 * wr + r) * 16 + quad * 4;
      int cg    = ibase >> 3;
#pragma unroll
      for (int c2 = 0; c2 < 2; ++c2) {
        int jg  = (2 * wc + c2) * 16 + (lane & 15);
        int idx = jg * 128 + ((cg ^ (jg & 15)) << 3) + (ibase & 7);
        s16x4 vh, vl;
#pragma unroll
        for (int e = 0; e < 4; ++e) {
          float mv = -kB * acc[r][c2][e] + ((ibase + e == jg) ? kA : 0.f);
          mv = fminf(fmaxf(mv, -4.f), 4.f);
          unsigned short hh = f2bf(mv);
          vh[e] = (short)hh;
          vl[e] = (short)f2bf(mv - bf2f(hh));
        }
        *(s16x4*)(Mh + idx) = vh;
        *(s16x4*)(Ml + idx) = vl;
      }
    }
    __syncthreads();

    // --- (c) Y' = M*Y, Z' = M*Z (M = shared A operand; iterates commute) ---
    f32x4 ay[4][2], az[4][2];
#pragma unroll
    for (int r = 0; r < 4; ++r)
#pragma unroll
      for (int c2 = 0; c2 < 2; ++c2) { ay[r][c2] = (f32x4)0.f; az[r][c2] = (f32x4)0.f; }
#pragma unroll
    for (int ks = 0; ks < 4; ++ks) {
      s16x8 aMh[4], aMl[4], bYh[2], bYl[2], bZ[2];
#pragma unroll
      for (int r = 0; r < 4; ++r) {
        int rb = (4 * wr + r) * 16;
        aMh[r] = load_frag(Mh, rb, ks, lane);
        aMl[r] = load_frag(Ml, rb, ks, lane);
      }
#pragma unroll
      for (int c2 = 0; c2 < 2; ++c2) {
        int cb = (2 * wc + c2) * 16;
        bYh[c2] = load_frag(Yh, cb, ks, lane);
        bYl[c2] = load_frag(Yl, cb, ks, lane);
        bZ[c2]  = load_frag(Zb, cb, ks, lane);
      }
#pragma unroll
      for (int r = 0; r < 4; ++r)
#pragma unroll
        for (int c2 = 0; c2 < 2; ++c2) {
          ay[r][c2] = __builtin_amdgcn_mfma_f32_16x16x32_bf16(aMh[r], bYh[c2], ay[r][c2], 0, 0, 0);
          ay[r][c2] = __builtin_amdgcn_mfma_f32_16x16x32_bf16(aMh[r], bYl[c2], ay[r][c2], 0, 0, 0);
          ay[r][c2] = __builtin_amdgcn_mfma_f32_16x16x32_bf16(aMl[r], bYh[c2], ay[r][c2], 0, 0, 0);
          az[r][c2] = __builtin_amdgcn_mfma_f32_16x16x32_bf16(aMh[r], bZ[c2],  az[r][c2], 0, 0, 0);
          az[r][c2] = __builtin_amdgcn_mfma_f32_16x16x32_bf16(aMl[r], bZ[c2],  az[r][c2], 0, 0, 0);
        }
    }
    __syncthreads();

    // --- (d) store Y' (hi/lo), Z' (single), transposed ---
#pragma unroll
    for (int r = 0; r < 4; ++r) {
      int ibase = (4 * wr + r) * 16 + quad * 4;
      int cg    = ibase >> 3;
#pragma unroll
      for (int c2 = 0; c2 < 2; ++c2) {
        int jg  = (2 * wc + c2) * 16 + (lane & 15);
        int idx = jg * 128 + ((cg ^ (jg & 15)) << 3) + (ibase & 7);
        s16x4 vh, vl, vz;
#pragma unroll
        for (int e = 0; e < 4; ++e) {
          float yv = ay[r][c2][e];
          unsigned short hh = f2bf(yv);
          vh[e] = (short)hh;
          vl[e] = (short)f2bf(yv - bf2f(hh));
          vz[e] = (short)f2bf(az[r][c2][e]);
        }
        *(s16x4*)(Yh + idx) = vh;
        *(s16x4*)(Yl + idx) = vl;
        *(s16x4*)(Zb + idx) = vz;
      }
    }
    __syncthreads();
  }

  // ---- traces: tr(GZ) (fp32 anchor from garr), tr(Z), tr(Z^3) ----
  float t_gz = 0.f, t_z = 0.f, t_z3 = 0.f;
  if (bid < NCLS) {
#pragma unroll
    for (int a = 0; a < 8; ++a) {
      s16x4 zv = *(const s16x4*)(Zb + swz_idx(i0 + a, j0g));
#pragma unroll
      for (int e = 0; e < 4; ++e) t_gz += garr[a * 4 + e] * bf2f((unsigned short)zv[e]);
    }
  } else {
#pragma unroll
    for (int t = 0; t < 8; ++t) {
      int flat = 4 * (tid + 512 * t), i = flat >> 7, j0 = flat & 127;
      s16x4 zv = *(const s16x4*)(Zb + swz_idx(i, j0));
#pragma unroll
      for (int e = 0; e < 4; ++e) t_gz += garr[t * 4 + e] * bf2f((unsigned short)zv[e]);
    }
  }
  if (tid < DIM) t_z = bf2f((unsigned short)Zb[swz_idx(tid, tid)]);

  {  // U = Z*Z tile-wise; tr(Z^3) = sum U_ij * Z_ji
    f32x4 u[4][2];
#pragma unroll
    for (int r = 0; r < 4; ++r)
#pragma unroll
      for (int c2 = 0; c2 < 2; ++c2) u[r][c2] = (f32x4)0.f;
#pragma unroll
    for (int ks = 0; ks < 4; ++ks) {
      s16x8 a[4], b[2];
#pragma unroll
      for (int r = 0; r < 4; ++r) a[r] = load_frag(Zb, (4 * wr + r) * 16, ks, lane);
#pragma unroll
      for (int c2 = 0; c2 < 2; ++c2) b[c2] = load_frag(Zb, (2 * wc + c2) * 16, ks, lane);
#pragma unroll
      for (int r = 0; r < 4; ++r)
#pragma unroll
        for (int c2 = 0; c2 < 2; ++c2)
          u[r][c2] = __builtin_amdgcn_mfma_f32_16x16x32_bf16(a[r], b[c2], u[r][c2], 0, 0, 0);
    }
#pragma unroll
    for (int r = 0; r < 4; ++r) {
      int ibase = (4 * wr + r) * 16 + quad * 4;
      int cg    = ibase >> 3;
#pragma unroll
      for (int c2 = 0; c2 < 2; ++c2) {
        int jg  = (2 * wc + c2) * 16 + (lane & 15);
        int idx = jg * 128 + ((cg ^ (jg & 15)) << 3) + (ibase & 7);
        s16x4 zt = *(const s16x4*)(Zb + idx);
#pragma unroll
        for (int e = 0; e < 4; ++e) t_z3 += u[r][c2][e] * bf2f((unsigned short)zt[e]);
      }
    }
  }

  for (int off = 32; off > 0; off >>= 1) {
    t_gz += __shfl_down(t_gz, off, 64);
    t_z  += __shfl_down(t_z,  off, 64);
    t_z3 += __shfl_down(t_z3, off, 64);
  }
  __syncthreads();
  float* red = (float*)Mh;             // Mh dead after last iter
  if (lane == 0) { red[wv] = t_gz; red[8 + wv] = t_z; red[16 + wv] = t_z3; }
  __syncthreads();

  float nuc_own = 0.f;
  if (tid == 0) {
    float gz = 0.f, z1 = 0.f, z3 = 0.f;
#pragma unroll
    for (int w = 0; w < 8; ++w) { gz += red[w]; z1 += red[8 + w]; z3 += red[16 + w]; }
    float trsq = gz * invs + 0.5f * eps * z1 - 0.125f * eps * eps * z3;
    nuc_own = sqrtf(s) * trsq;
    nuc[bid] = nuc_own;
  }

  if (bid < NCLS) {
    if (tid == 0) flag_set(&nflag[bid]);
    return;
  }

  // ======================= block 64: final combine ======================
  if (tid == 0) {
    for (int c = 0; c < NCLS; ++c) flag_wait(&nflag[c]);
    for (int b = 0; b < NCEB; ++b)  flag_wait(&cflag[b]);
  }
  __syncthreads();

  float ce2 = cepart[tid] + ((tid < NCEW - 512) ? cepart[512 + tid] : 0.f);
  float vmx = (tid < NCLS) ? fmaxf(nuc[tid], DELTA_) : 0.f;
  for (int off = 32; off > 0; off >>= 1) {
    vmx += __shfl_down(vmx, off, 64);
    ce2 += __shfl_down(ce2, off, 64);
  }
  if (lane == 0) { red[wv] = vmx; red[8 + wv] = ce2; }
  __syncthreads();
  if (tid == 0) {
    float vs = 0.f, cs = 0.f;
#pragma unroll
    for (int w = 0; w < 8; ++w) { vs += red[w]; cs += red[8 + w]; }
    float ole = (vs - nuc_own) * (LAMBDA_ / (float)N_ROWS);
    out[0] = ole + cs / (float)N_ROWS;
  }
}

extern "C" void kernel_launch(void* const* d_in, const int* in_sizes, int n_in,
                              void* d_out, int out_size, void* d_ws, size_t ws_size,
                              hipStream_t stream) {
  const float* logits = (const float*)d_in[0];   // out  [8192,64]
  const float* feat   = (const float*)d_in[1];   // feat [8192,128]
  const int*   yp     = (const int*)d_in[2];     // y    [8192]

  float* G      = (float*)d_ws;                  // 64 class mats + Gall (idx 64)
  float* nuc    = G + (size_t)NMAT * DIM * DIM;  // 65
  float* cepart = nuc + NMAT + 2;                // 1016
  int*   gflag  = (int*)(cepart + NCEW);         // 64
  int*   gallf  = gflag + NCLS;                  // 16
  int*   nflag  = gallf + 16;                    // 64
  int*   cflag  = nflag + NCLS;                  // 127

  ole_mono<<<NCLS + 1 + NCEB, 512, 0, stream>>>(feat, yp, logits, G, nuc,
                                                cepart, gflag, gallf, nflag,
                                                cflag, (float*)d_out);
}

// Round 12
// 157.795 us; speedup vs baseline: 3.0426x; 3.0426x over previous
//
#include <hip/hip_runtime.h>
#include <math.h>

// OLE loss on MI355X — 2 dispatches.
// ||X_c||* = trace(sqrt(G_c)), G_c = X_c^T X_c (128x128).
// K1: blocks 0..63 per-class Gram -> G_c; blocks 64..191 CE -> cepart.
//     (no flags, no spins; kernel boundary = visibility barrier)
// K2: blocks 65..80 Gall slices -> magic flag; blocks 0..63 NS(G_c) ->
//     nuc + magic flag; block 64 parallel-waits 16 gallf (lane b polls
//     flag b), NS(Gall), parallel-waits 64 nflag, final combine.
// Lessons encoded: R8 grid.sync ~50us/barrier -> avoid; R11 SERIAL flag
// polling ~0.5-1us each -> poll one flag per lane in parallel.
// NS: Y,M split bf16 hi/lo, Z single bf16, Frobenius norm, scaled ladder
// (9 iters), trace anchored on fp32 G.

#define N_ROWS 8192
#define DIM    128
#define NCLS   64
#define NMAT   65
#define NITER  9
#define EPSN   2e-4f
#define LAMBDA_ 0.25f
#define DELTA_  1.0f
#define MAGIC  0x13579BDF   // != 0xAAAAAAAA poison, != 0

typedef __attribute__((ext_vector_type(8))) short s16x8;  // 8 bf16 = 4 VGPR
typedef __attribute__((ext_vector_type(4))) short s16x4;  // 4 bf16
typedef __attribute__((ext_vector_type(4))) float f32x4;

// Scaled-NS ladder: M_k = C1[k]*I - C2[k]*W, C1 = 1.5*sqrt(t), C2 = 0.5*t^1.5.
// t = [2.9, 2.758, 2.13, 1.868, 1.264, 1,1,1,1]; u = t*w, w' = u(1.5-u/2)^2
// stays in (0,1] for u in (0,3) -> sign-safe; final t=1 steps polish w->1.
static __device__ const float NS_C1[NITER] =
  {2.554408f, 2.491084f, 2.189178f, 2.050122f, 1.686417f, 1.5f, 1.5f, 1.5f, 1.5f};
static __device__ const float NS_C2[NITER] =
  {2.469261f, 2.290137f, 1.554316f, 1.276543f, 0.710544f, 0.5f, 0.5f, 0.5f, 0.5f};

__device__ __forceinline__ unsigned short f2bf(float f) {   // RNE
  unsigned u = __float_as_uint(f);
  u = (u + 0x7FFFu + ((u >> 16) & 1u)) >> 16;
  return (unsigned short)u;
}
__device__ __forceinline__ float bf2f(unsigned short h) {
  return __uint_as_float(((unsigned)h) << 16);
}

// bf16 LDS: element (i,j) at short-index i*128 + (((j>>3)^(i&15))<<3) + (j&7)
__device__ __forceinline__ int swz_idx(int i, int j) {
  return i * 128 + (((j >> 3) ^ (i & 15)) << 3) + (j & 7);
}

__device__ __forceinline__ s16x8 load_frag(const short* buf, int row0,
                                           int kstep, int lane) {
  int m  = row0 + (lane & 15);
  int kg = kstep * 4 + (lane >> 4);
  return *(const s16x8*)(buf + m * 128 + ((kg ^ (m & 15)) << 3));
}

__device__ __forceinline__ void flag_set(int* p) {
  __threadfence();
  __hip_atomic_store(p, MAGIC, __ATOMIC_RELEASE, __HIP_MEMORY_SCOPE_AGENT);
}
__device__ __forceinline__ void flag_wait(const int* p) {
  while (__hip_atomic_load(p, __ATOMIC_ACQUIRE, __HIP_MEMORY_SCOPE_AGENT) != MAGIC)
    __builtin_amdgcn_s_sleep(8);
}

// ---------------------------------------------------------------------------
// Kernel 1: blocks 0..63 = per-class Gram; blocks 64..191 = cross-entropy.
// (R7-proven; zero inter-block communication.)
// ---------------------------------------------------------------------------
__global__ __launch_bounds__(256) void ole_gram_ce(const float* __restrict__ feat,
                                                   const int* __restrict__ y,
                                                   const float* __restrict__ logits,
                                                   float* __restrict__ G,
                                                   float* __restrict__ cepart) {
  __shared__ int   list[N_ROWS];
  __shared__ int   cnt;
  __shared__ float xs[8][DIM];

  const int tid = threadIdx.x;

  if (blockIdx.x >= NCLS) {
    // ---------------- CE path (128 blocks, 512 waves) ----------------
    const int blk    = blockIdx.x - NCLS;
    const int gwave  = blk * 4 + (tid >> 6);
    const int lane   = tid & 63;

    float acc = 0.f;
    for (int row = gwave; row < N_ROWS; row += 512) {
      float v = logits[row * NCLS + lane];
      float mx = v;
      for (int off = 32; off > 0; off >>= 1) mx = fmaxf(mx, __shfl_xor(mx, off, 64));
      float e = expf(v - mx);
      for (int off = 32; off > 0; off >>= 1) e += __shfl_xor(e, off, 64);
      if (lane == 0) {
        int t = y[row];
        acc += (mx + logf(e)) - logits[row * NCLS + t];
      }
    }
    if (lane == 0) cepart[gwave] = acc;
    return;
  }

  // ---------------- gram path (64 blocks) ----------------
  const int c  = blockIdx.x;
  const int ti = tid >> 4, tj = tid & 15;
  const int i0 = ti * 8,  j0 = tj * 8;

  if (tid == 0) cnt = 0;
  __syncthreads();
  const int4* y4 = (const int4*)y;
#pragma unroll
  for (int t = 0; t < 8; ++t) {
    int g4 = tid + 256 * t;
    int4 v = y4[g4];
    int r0 = g4 * 4;
    if (v.x == c) list[atomicAdd(&cnt, 1)] = r0;
    if (v.y == c) list[atomicAdd(&cnt, 1)] = r0 + 1;
    if (v.z == c) list[atomicAdd(&cnt, 1)] = r0 + 2;
    if (v.w == c) list[atomicAdd(&cnt, 1)] = r0 + 3;
  }
  __syncthreads();
  const int n = cnt;

  float acc[8][8];
#pragma unroll
  for (int a = 0; a < 8; ++a)
#pragma unroll
    for (int b = 0; b < 8; ++b) acc[a][b] = 0.f;

  const int ldrow = tid >> 5;
  const int ldcol = (tid & 31) * 4;

  for (int base = 0; base < n; base += 8) {
    __syncthreads();
    int li = base + ldrow;
    float4 v = make_float4(0.f, 0.f, 0.f, 0.f);
    if (li < n) v = *(const float4*)(feat + (size_t)list[li] * DIM + ldcol);
    *(float4*)(&xs[ldrow][ldcol]) = v;
    __syncthreads();
#pragma unroll
    for (int rw = 0; rw < 8; ++rw) {
      float xi[8], xj[8];
#pragma unroll
      for (int a = 0; a < 8; ++a) xi[a] = xs[rw][i0 + a];
#pragma unroll
      for (int b = 0; b < 8; ++b) xj[b] = xs[rw][j0 + b];
#pragma unroll
      for (int a = 0; a < 8; ++a)
#pragma unroll
        for (int b = 0; b < 8; ++b) acc[a][b] = fmaf(xi[a], xj[b], acc[a][b]);
    }
  }

  float* Gc = G + (size_t)c * DIM * DIM;
#pragma unroll
  for (int a = 0; a < 8; ++a)
#pragma unroll
    for (int b = 0; b < 8; ++b)
      Gc[(i0 + a) * DIM + (j0 + b)] = acc[a][b];
}

// ---------------------------------------------------------------------------
// Kernel 2: 81 blocks x 512.
//  blocks 65..80: Gall slice (reads kernel-1 G, waits on nothing) -> gallf
//  blocks 0..63:  NS(G_c) -> nuc[c] -> nflag[c]
//  block 64:      parallel-wait gallf -> NS(Gall) -> parallel-wait nflag
//                 -> final combine -> out
// ---------------------------------------------------------------------------
__global__ __launch_bounds__(512, 1) void ole_ns(const float* __restrict__ G,
                                                 float* __restrict__ Gmut,
                                                 float* __restrict__ nuc,
                                                 const float* __restrict__ cepart,
                                                 int* __restrict__ gallf,
                                                 int* __restrict__ nflag,
                                                 float* __restrict__ out) {
  __shared__ short Yh[DIM * DIM];
  __shared__ short Yl[DIM * DIM];
  __shared__ short Mh[DIM * DIM];
  __shared__ short Ml[DIM * DIM];
  __shared__ short Zb[DIM * DIM];

  const int bid  = blockIdx.x;
  const int tid  = threadIdx.x;
  const int lane = tid & 63;
  const int quad = lane >> 4;
  const int wv   = tid >> 6;    // 0..7

  // ---------------- Gall-builder blocks (65..80) ----------------
  if (bid > NCLS) {
    const int gb = bid - NCLS - 1;        // 0..15
    if (tid < 256) {
      int idx4 = gb * 256 + tid;          // 16 x 256 = 4096 float4s
      const float4* G4 = (const float4*)G;
      float4 s = make_float4(0.f, 0.f, 0.f, 0.f);
#pragma unroll 8
      for (int c = 0; c < NCLS; ++c) {
        float4 v = G4[(size_t)c * (DIM * DIM / 4) + idx4];
        s.x += v.x; s.y += v.y; s.z += v.z; s.w += v.w;
      }
      ((float4*)Gmut)[(size_t)NCLS * (DIM * DIM / 4) + idx4] = s;
    }
    __syncthreads();
    if (tid == 0) flag_set(&gallf[gb]);
    return;
  }

  // ---------------- block 64: wait for Gall (parallel poll) ----------------
  if (bid == NCLS) {
    if (tid < 16) flag_wait(&gallf[tid]);   // one flag per lane
    __syncthreads();
  }

  const int wr = wv >> 2;     // 0..1 -> tile-rows 4*wr..4*wr+3
  const int wc = wv & 3;      // 0..3 -> tile-cols 2*wc..2*wc+1

  const float4* Gm4 = (const float4*)(G + (size_t)bid * DIM * DIM);

  // ---- load G (8 float4/thread), in-block trace + fro2 ----
  float4 gs[8];
  float tpart = 0.f, fpart = 0.f;
#pragma unroll
  for (int t = 0; t < 8; ++t) {
    int idx4 = tid + 512 * t;
    float4 v = Gm4[idx4];
    gs[t] = v;
    fpart += v.x * v.x + v.y * v.y + v.z * v.z + v.w * v.w;
    int flat = idx4 * 4, i = flat >> 7, j0 = flat & 127;
    if (j0 <= i && i < j0 + 4) tpart += ((const float*)&v)[i - j0];
  }
  for (int off = 32; off > 0; off >>= 1) {
    tpart += __shfl_down(tpart, off, 64);
    fpart += __shfl_down(fpart, off, 64);
  }
  float* redf = (float*)Zb;           // Zb not yet initialized
  if (lane == 0) { redf[wv] = tpart; redf[8 + wv] = fpart; }
  __syncthreads();
  float trace = 0.f, fro2 = 0.f;
#pragma unroll
  for (int w = 0; w < 8; ++w) { trace += redf[w]; fro2 += redf[8 + w]; }
  __syncthreads();                    // redf reads done -> Zb reusable

  float s = sqrtf(fro2);
  if (s < 1e-12f) s = 1.f;
  const float invs = 1.f / s;
  const float eps  = EPSN * trace * invs;

  // ---- init: Y0 = G/s + eps*I (hi/lo), Z0 = I ----
#pragma unroll
  for (int t = 0; t < 8; ++t) {
    int idx4 = tid + 512 * t;
    int flat = idx4 * 4, i = flat >> 7, j0 = flat & 127;
    s16x4 vh, vl;
#pragma unroll
    for (int e = 0; e < 4; ++e) {
      float x = ((const float*)&gs[t])[e] * invs + ((i == j0 + e) ? eps : 0.f);
      unsigned short hh = f2bf(x);
      vh[e] = (short)hh;
      vl[e] = (short)f2bf(x - bf2f(hh));
    }
    int idx = swz_idx(i, j0);
    *(s16x4*)(Yh + idx) = vh;
    *(s16x4*)(Yl + idx) = vl;
  }
  for (int grp = tid; grp < DIM * 16; grp += 512) {
    int i = grp >> 4, g = grp & 15;
    s16x8 v = (s16x8)0;
    if ((i >> 3) == g) v[i & 7] = (short)0x3F80;   // 1.0 bf16
    *(s16x8*)(Zb + i * 128 + ((g ^ (i & 15)) << 3)) = v;
  }
  __syncthreads();

  for (int it = 0; it < NITER; ++it) {
    const float kA = NS_C1[it];
    const float kB = NS_C2[it];

    // --- (a) W = Z*Y (Yh+Yl) ---
    f32x4 acc[4][2];
#pragma unroll
    for (int r = 0; r < 4; ++r)
#pragma unroll
      for (int c2 = 0; c2 < 2; ++c2) acc[r][c2] = (f32x4)0.f;
#pragma unroll
    for (int ks = 0; ks < 4; ++ks) {
      s16x8 a[4], bh[2], bl[2];
#pragma unroll
      for (int r = 0; r < 4; ++r) a[r] = load_frag(Zb, (4 * wr + r) * 16, ks, lane);
#pragma unroll
      for (int c2 = 0; c2 < 2; ++c2) {
        bh[c2] = load_frag(Yh, (2 * wc + c2) * 16, ks, lane);
        bl[c2] = load_frag(Yl, (2 * wc + c2) * 16, ks, lane);
      }
#pragma unroll
      for (int r = 0; r < 4; ++r)
#pragma unroll
        for (int c2 = 0; c2 < 2; ++c2) {
          acc[r][c2] = __builtin_amdgcn_mfma_f32_16x16x32_bf16(a[r], bh[c2], acc[r][c2], 0, 0, 0);
          acc[r][c2] = __builtin_amdgcn_mfma_f32_16x16x32_bf16(a[r], bl[c2], acc[r][c2], 0, 0, 0);
        }
    }
    // --- (b) M = kA*I - kB*W, clamp, hi/lo split, transposed store ---
#pragma unroll
    for (int r = 0; r < 4; ++r) {
      int ibase = (4 * wr + r) * 16 + quad * 4;
      int cg    = ibase >> 3;
#pragma unroll
      for (int c2 = 0; c2 < 2; ++c2) {
        int jg  = (2 * wc + c2) * 16 + (lane & 15);
        int idx = jg * 128 + ((cg ^ (jg & 15)) << 3) + (ibase & 7);
        s16x4 vh, vl;
#pragma unroll
        for (int e = 0; e < 4; ++e) {
          float mv = -kB * acc[r][c2][e] + ((ibase + e == jg) ? kA : 0.f);
          mv = fminf(fmaxf(mv, -4.f), 4.f);
          unsigned short hh = f2bf(mv);
          vh[e] = (short)hh;
          vl[e] = (short)f2bf(mv - bf2f(hh));
        }
        *(s16x4*)(Mh + idx) = vh;
        *(s16x4*)(Ml + idx) = vl;
      }
    }
    __syncthreads();

    // --- (c) Y' = M*Y, Z' = M*Z (M = shared A operand; iterates commute) ---
    f32x4 ay[4][2], az[4][2];
#pragma unroll
    for (int r = 0; r < 4; ++r)
#pragma unroll
      for (int c2 = 0; c2 < 2; ++c2) { ay[r][c2] = (f32x4)0.f; az[r][c2] = (f32x4)0.f; }
#pragma unroll
    for (int ks = 0; ks < 4; ++ks) {
      s16x8 aMh[4], aMl[4], bYh[2], bYl[2], bZ[2];
#pragma unroll
      for (int r = 0; r < 4; ++r) {
        int rb = (4 * wr + r) * 16;
        aMh[r] = load_frag(Mh, rb, ks, lane);
        aMl[r] = load_frag(Ml, rb, ks, lane);
      }
#pragma unroll
      for (int c2 = 0; c2 < 2; ++c2) {
        int cb = (2 * wc + c2) * 16;
        bYh[c2] = load_frag(Yh, cb, ks, lane);
        bYl[c2] = load_frag(Yl, cb, ks, lane);
        bZ[c2]  = load_frag(Zb, cb, ks, lane);
      }
#pragma unroll
      for (int r = 0; r < 4; ++r)
#pragma unroll
        for (int c2 = 0; c2 < 2; ++c2) {
          ay[r][c2] = __builtin_amdgcn_mfma_f32_16x16x32_bf16(aMh[r], bYh[c2], ay[r][c2], 0, 0, 0);
          ay[r][c2] = __builtin_amdgcn_mfma_f32_16x16x32_bf16(aMh[r], bYl[c2], ay[r][c2], 0, 0, 0);
          ay[r][c2] = __builtin_amdgcn_mfma_f32_16x16x32_bf16(aMl[r], bYh[c2], ay[r][c2], 0, 0, 0);
          az[r][c2] = __builtin_amdgcn_mfma_f32_16x16x32_bf16(aMh[r], bZ[c2],  az[r][c2], 0, 0, 0);
          az[r][c2] = __builtin_amdgcn_mfma_f32_16x16x32_bf16(aMl[r], bZ[c2],  az[r][c2], 0, 0, 0);
        }
    }
    __syncthreads();

    // --- (d) store Y' (hi/lo), Z' (single), transposed ---
#pragma unroll
    for (int r = 0; r < 4; ++r) {
      int ibase = (4 * wr + r) * 16 + quad * 4;
      int cg    = ibase >> 3;
#pragma unroll
      for (int c2 = 0; c2 < 2; ++c2) {
        int jg  = (2 * wc + c2) * 16 + (lane & 15);
        int idx = jg * 128 + ((cg ^ (jg & 15)) << 3) + (ibase & 7);
        s16x4 vh, vl, vz;
#pragma unroll
        for (int e = 0; e < 4; ++e) {
          float yv = ay[r][c2][e];
          unsigned short hh = f2bf(yv);
          vh[e] = (short)hh;
          vl[e] = (short)f2bf(yv - bf2f(hh));
          vz[e] = (short)f2bf(az[r][c2][e]);
        }
        *(s16x4*)(Yh + idx) = vh;
        *(s16x4*)(Yl + idx) = vl;
        *(s16x4*)(Zb + idx) = vz;
      }
    }
    __syncthreads();
  }

  // ---- traces: tr(GZ) (fp32 G anchor), tr(Z), tr(Z^3) ----
  float t_gz = 0.f, t_z = 0.f, t_z3 = 0.f;
#pragma unroll
  for (int t = 0; t < 8; ++t) {
    int idx4 = tid + 512 * t;
    int flat = idx4 * 4, i = flat >> 7, j0 = flat & 127;
    s16x4 zv = *(const s16x4*)(Zb + swz_idx(i, j0));
#pragma unroll
    for (int e = 0; e < 4; ++e) t_gz += ((const float*)&gs[t])[e] * bf2f((unsigned short)zv[e]);
  }
  if (tid < DIM) t_z = bf2f((unsigned short)Zb[swz_idx(tid, tid)]);

  {  // U = Z*Z tile-wise; tr(Z^3) = sum U_ij * Z_ji
    f32x4 u[4][2];
#pragma unroll
    for (int r = 0; r < 4; ++r)
#pragma unroll
      for (int c2 = 0; c2 < 2; ++c2) u[r][c2] = (f32x4)0.f;
#pragma unroll
    for (int ks = 0; ks < 4; ++ks) {
      s16x8 a[4], b[2];
#pragma unroll
      for (int r = 0; r < 4; ++r) a[r] = load_frag(Zb, (4 * wr + r) * 16, ks, lane);
#pragma unroll
      for (int c2 = 0; c2 < 2; ++c2) b[c2] = load_frag(Zb, (2 * wc + c2) * 16, ks, lane);
#pragma unroll
      for (int r = 0; r < 4; ++r)
#pragma unroll
        for (int c2 = 0; c2 < 2; ++c2)
          u[r][c2] = __builtin_amdgcn_mfma_f32_16x16x32_bf16(a[r], b[c2], u[r][c2], 0, 0, 0);
    }
#pragma unroll
    for (int r = 0; r < 4; ++r) {
      int ibase = (4 * wr + r) * 16 + quad * 4;
      int cg    = ibase >> 3;
#pragma unroll
      for (int c2 = 0; c2 < 2; ++c2) {
        int jg  = (2 * wc + c2) * 16 + (lane & 15);
        int idx = jg * 128 + ((cg ^ (jg & 15)) << 3) + (ibase & 7);
        s16x4 zt = *(const s16x4*)(Zb + idx);
#pragma unroll
        for (int e = 0; e < 4; ++e) t_z3 += u[r][c2][e] * bf2f((unsigned short)zt[e]);
      }
    }
  }

  for (int off = 32; off > 0; off >>= 1) {
    t_gz += __shfl_down(t_gz, off, 64);
    t_z  += __shfl_down(t_z,  off, 64);
    t_z3 += __shfl_down(t_z3, off, 64);
  }
  __syncthreads();
  float* red = (float*)Mh;             // Mh dead after last iter
  if (lane == 0) { red[wv] = t_gz; red[8 + wv] = t_z; red[16 + wv] = t_z3; }
  __syncthreads();

  float nuc_own = 0.f;
  if (tid == 0) {
    float gz = 0.f, z1 = 0.f, z3 = 0.f;
#pragma unroll
    for (int w = 0; w < 8; ++w) { gz += red[w]; z1 += red[8 + w]; z3 += red[16 + w]; }
    float trsq = gz * invs + 0.5f * eps * z1 - 0.125f * eps * eps * z3;
    nuc_own = sqrtf(s) * trsq;
    nuc[bid] = nuc_own;
  }

  if (bid < NCLS) {
    if (tid == 0) flag_set(&nflag[bid]);
    return;
  }

  // ======== block 64: final combine (parallel poll, one flag/lane) ========
  if (tid < NCLS) flag_wait(&nflag[tid]);
  __syncthreads();

  float ce2 = cepart[tid];                       // 512 entries, 512 threads
  float vmx = (tid < NCLS) ? fmaxf(nuc[tid], DELTA_) : 0.f;
  for (int off = 32; off > 0; off >>= 1) {
    vmx += __shfl_down(vmx, off, 64);
    ce2 += __shfl_down(ce2, off, 64);
  }
  if (lane == 0) { red[wv] = vmx; red[8 + wv] = ce2; }
  __syncthreads();
  if (tid == 0) {
    float vs = 0.f, cs = 0.f;
#pragma unroll
    for (int w = 0; w < 8; ++w) { vs += red[w]; cs += red[8 + w]; }
    float ole = (vs - nuc_own) * (LAMBDA_ / (float)N_ROWS);
    out[0] = ole + cs / (float)N_ROWS;
  }
}

extern "C" void kernel_launch(void* const* d_in, const int* in_sizes, int n_in,
                              void* d_out, int out_size, void* d_ws, size_t ws_size,
                              hipStream_t stream) {
  const float* logits = (const float*)d_in[0];   // out  [8192,64]
  const float* feat   = (const float*)d_in[1];   // feat [8192,128]
  const int*   yp     = (const int*)d_in[2];     // y    [8192]

  float* G      = (float*)d_ws;                  // 64 class mats + Gall (idx 64)
  float* nuc    = G + (size_t)NMAT * DIM * DIM;  // 65 (+pad)
  float* cepart = nuc + NMAT + 3;                // 512
  int*   gallf  = (int*)(cepart + 512);          // 16
  int*   nflag  = gallf + 16;                    // 64

  ole_gram_ce<<<NCLS + 128, 256, 0, stream>>>(feat, yp, logits, G, cepart);
  ole_ns<<<NMAT + 16, 512, 0, stream>>>(G, G, nuc, cepart, gallf, nflag,
                                        (float*)d_out);
}

// Round 13
// 141.566 us; speedup vs baseline: 3.3914x; 1.1146x over previous
//
#include <hip/hip_runtime.h>
#include <math.h>

// OLE loss on MI355X — 2 dispatches (R12 structure).
// ||X_c||* = trace(sqrt(G_c)), G_c = X_c^T X_c (128x128).
// K1: blocks 0..63 per-class Gram -> G_c; blocks 64..191 CE -> cepart.
// K2: blocks 65..80 Gall slices -> magic flag; blocks 0..63 NS(G_c) ->
//     nuc + magic flag; block 64 parallel-waits gallf (one flag/lane),
//     NS(Gall), parallel-waits nflag, final combine.
// R13: NITER 9->8 (iter-count is the only thing that scales — R7 evidence);
// Y stored SINGLE bf16 (noise into weak modes ~1.5e-5 << eps_norm 1.6e-3
// under Frobenius normalization; M keeps hi/lo split — that one matters).
// Lessons: R8 grid.sync ~50us/barrier; R11 serial flag polls ~1us each ->
// poll one flag per lane.

#define N_ROWS 8192
#define DIM    128
#define NCLS   64
#define NMAT   65
#define NITER  8
#define EPSN   2e-4f
#define LAMBDA_ 0.25f
#define DELTA_  1.0f
#define MAGIC  0x13579BDF   // != 0xAAAAAAAA poison, != 0

typedef __attribute__((ext_vector_type(8))) short s16x8;  // 8 bf16 = 4 VGPR
typedef __attribute__((ext_vector_type(4))) short s16x4;  // 4 bf16
typedef __attribute__((ext_vector_type(4))) float f32x4;

// Scaled-NS ladder: M_k = C1[k]*I - C2[k]*W, C1 = 1.5*sqrt(t), C2 = 0.5*t^1.5.
// t = [2.9, 2.758, 2.13, 1.868, 1.264, 1,1,1]; u = t*w, w' = u(1.5-u/2)^2
// stays in [0,1] for u in (0,3) -> sign-safe; final t=1 steps polish w->1.
// (strong modes crushed at k0 regrow and converge by k6; weak modes by k6.)
static __device__ const float NS_C1[NITER] =
  {2.554408f, 2.491084f, 2.189178f, 2.050122f, 1.686417f, 1.5f, 1.5f, 1.5f};
static __device__ const float NS_C2[NITER] =
  {2.469261f, 2.290137f, 1.554316f, 1.276543f, 0.710544f, 0.5f, 0.5f, 0.5f};

__device__ __forceinline__ unsigned short f2bf(float f) {   // RNE
  unsigned u = __float_as_uint(f);
  u = (u + 0x7FFFu + ((u >> 16) & 1u)) >> 16;
  return (unsigned short)u;
}
__device__ __forceinline__ float bf2f(unsigned short h) {
  return __uint_as_float(((unsigned)h) << 16);
}

// bf16 LDS: element (i,j) at short-index i*128 + (((j>>3)^(i&15))<<3) + (j&7)
__device__ __forceinline__ int swz_idx(int i, int j) {
  return i * 128 + (((j >> 3) ^ (i & 15)) << 3) + (j & 7);
}

__device__ __forceinline__ s16x8 load_frag(const short* buf, int row0,
                                           int kstep, int lane) {
  int m  = row0 + (lane & 15);
  int kg = kstep * 4 + (lane >> 4);
  return *(const s16x8*)(buf + m * 128 + ((kg ^ (m & 15)) << 3));
}

__device__ __forceinline__ void flag_set(int* p) {
  __threadfence();
  __hip_atomic_store(p, MAGIC, __ATOMIC_RELEASE, __HIP_MEMORY_SCOPE_AGENT);
}
__device__ __forceinline__ void flag_wait(const int* p) {
  while (__hip_atomic_load(p, __ATOMIC_ACQUIRE, __HIP_MEMORY_SCOPE_AGENT) != MAGIC)
    __builtin_amdgcn_s_sleep(8);
}

// ---------------------------------------------------------------------------
// Kernel 1: blocks 0..63 = per-class Gram; blocks 64..191 = cross-entropy.
// (R7-proven; zero inter-block communication.)
// ---------------------------------------------------------------------------
__global__ __launch_bounds__(256) void ole_gram_ce(const float* __restrict__ feat,
                                                   const int* __restrict__ y,
                                                   const float* __restrict__ logits,
                                                   float* __restrict__ G,
                                                   float* __restrict__ cepart) {
  __shared__ int   list[N_ROWS];
  __shared__ int   cnt;
  __shared__ float xs[8][DIM];

  const int tid = threadIdx.x;

  if (blockIdx.x >= NCLS) {
    // ---------------- CE path (128 blocks, 512 waves) ----------------
    const int blk    = blockIdx.x - NCLS;
    const int gwave  = blk * 4 + (tid >> 6);
    const int lane   = tid & 63;

    float acc = 0.f;
    for (int row = gwave; row < N_ROWS; row += 512) {
      float v = logits[row * NCLS + lane];
      float mx = v;
      for (int off = 32; off > 0; off >>= 1) mx = fmaxf(mx, __shfl_xor(mx, off, 64));
      float e = expf(v - mx);
      for (int off = 32; off > 0; off >>= 1) e += __shfl_xor(e, off, 64);
      if (lane == 0) {
        int t = y[row];
        acc += (mx + logf(e)) - logits[row * NCLS + t];
      }
    }
    if (lane == 0) cepart[gwave] = acc;
    return;
  }

  // ---------------- gram path (64 blocks) ----------------
  const int c  = blockIdx.x;
  const int ti = tid >> 4, tj = tid & 15;
  const int i0 = ti * 8,  j0 = tj * 8;

  if (tid == 0) cnt = 0;
  __syncthreads();
  const int4* y4 = (const int4*)y;
#pragma unroll
  for (int t = 0; t < 8; ++t) {
    int g4 = tid + 256 * t;
    int4 v = y4[g4];
    int r0 = g4 * 4;
    if (v.x == c) list[atomicAdd(&cnt, 1)] = r0;
    if (v.y == c) list[atomicAdd(&cnt, 1)] = r0 + 1;
    if (v.z == c) list[atomicAdd(&cnt, 1)] = r0 + 2;
    if (v.w == c) list[atomicAdd(&cnt, 1)] = r0 + 3;
  }
  __syncthreads();
  const int n = cnt;

  float acc[8][8];
#pragma unroll
  for (int a = 0; a < 8; ++a)
#pragma unroll
    for (int b = 0; b < 8; ++b) acc[a][b] = 0.f;

  const int ldrow = tid >> 5;
  const int ldcol = (tid & 31) * 4;

  for (int base = 0; base < n; base += 8) {
    __syncthreads();
    int li = base + ldrow;
    float4 v = make_float4(0.f, 0.f, 0.f, 0.f);
    if (li < n) v = *(const float4*)(feat + (size_t)list[li] * DIM + ldcol);
    *(float4*)(&xs[ldrow][ldcol]) = v;
    __syncthreads();
#pragma unroll
    for (int rw = 0; rw < 8; ++rw) {
      float xi[8], xj[8];
#pragma unroll
      for (int a = 0; a < 8; ++a) xi[a] = xs[rw][i0 + a];
#pragma unroll
      for (int b = 0; b < 8; ++b) xj[b] = xs[rw][j0 + b];
#pragma unroll
      for (int a = 0; a < 8; ++a)
#pragma unroll
        for (int b = 0; b < 8; ++b) acc[a][b] = fmaf(xi[a], xj[b], acc[a][b]);
    }
  }

  float* Gc = G + (size_t)c * DIM * DIM;
#pragma unroll
  for (int a = 0; a < 8; ++a)
#pragma unroll
    for (int b = 0; b < 8; ++b)
      Gc[(i0 + a) * DIM + (j0 + b)] = acc[a][b];
}

// ---------------------------------------------------------------------------
// Kernel 2: 81 blocks x 512.
//  blocks 65..80: Gall slice (reads kernel-1 G, waits on nothing) -> gallf
//  blocks 0..63:  NS(G_c) -> nuc[c] -> nflag[c]
//  block 64:      parallel-wait gallf -> NS(Gall) -> parallel-wait nflag
//                 -> final combine -> out
// LDS: Yb (single), Mh, Ml, Zb = 4 x 32 KB = 128 KiB.
// ---------------------------------------------------------------------------
__global__ __launch_bounds__(512, 1) void ole_ns(const float* __restrict__ G,
                                                 float* __restrict__ Gmut,
                                                 float* __restrict__ nuc,
                                                 const float* __restrict__ cepart,
                                                 int* __restrict__ gallf,
                                                 int* __restrict__ nflag,
                                                 float* __restrict__ out) {
  __shared__ short Yb[DIM * DIM];
  __shared__ short Mh[DIM * DIM];
  __shared__ short Ml[DIM * DIM];
  __shared__ short Zb[DIM * DIM];

  const int bid  = blockIdx.x;
  const int tid  = threadIdx.x;
  const int lane = tid & 63;
  const int quad = lane >> 4;
  const int wv   = tid >> 6;    // 0..7

  // ---------------- Gall-builder blocks (65..80) ----------------
  if (bid > NCLS) {
    const int gb = bid - NCLS - 1;        // 0..15
    if (tid < 256) {
      int idx4 = gb * 256 + tid;          // 16 x 256 = 4096 float4s
      const float4* G4 = (const float4*)G;
      float4 s = make_float4(0.f, 0.f, 0.f, 0.f);
#pragma unroll 8
      for (int c = 0; c < NCLS; ++c) {
        float4 v = G4[(size_t)c * (DIM * DIM / 4) + idx4];
        s.x += v.x; s.y += v.y; s.z += v.z; s.w += v.w;
      }
      ((float4*)Gmut)[(size_t)NCLS * (DIM * DIM / 4) + idx4] = s;
    }
    __syncthreads();
    if (tid == 0) flag_set(&gallf[gb]);
    return;
  }

  // ---------------- block 64: wait for Gall (parallel poll) ----------------
  if (bid == NCLS) {
    if (tid < 16) flag_wait(&gallf[tid]);   // one flag per lane
    __syncthreads();
  }

  const int wr = wv >> 2;     // 0..1 -> tile-rows 4*wr..4*wr+3
  const int wc = wv & 3;      // 0..3 -> tile-cols 2*wc..2*wc+1

  const float4* Gm4 = (const float4*)(G + (size_t)bid * DIM * DIM);

  // ---- load G (8 float4/thread), in-block trace + fro2 ----
  float4 gs[8];
  float tpart = 0.f, fpart = 0.f;
#pragma unroll
  for (int t = 0; t < 8; ++t) {
    int idx4 = tid + 512 * t;
    float4 v = Gm4[idx4];
    gs[t] = v;
    fpart += v.x * v.x + v.y * v.y + v.z * v.z + v.w * v.w;
    int flat = idx4 * 4, i = flat >> 7, j0 = flat & 127;
    if (j0 <= i && i < j0 + 4) tpart += ((const float*)&v)[i - j0];
  }
  for (int off = 32; off > 0; off >>= 1) {
    tpart += __shfl_down(tpart, off, 64);
    fpart += __shfl_down(fpart, off, 64);
  }
  float* redf = (float*)Zb;           // Zb not yet initialized
  if (lane == 0) { redf[wv] = tpart; redf[8 + wv] = fpart; }
  __syncthreads();
  float trace = 0.f, fro2 = 0.f;
#pragma unroll
  for (int w = 0; w < 8; ++w) { trace += redf[w]; fro2 += redf[8 + w]; }
  __syncthreads();                    // redf reads done -> Zb reusable

  float s = sqrtf(fro2);
  if (s < 1e-12f) s = 1.f;
  const float invs = 1.f / s;
  const float eps  = EPSN * trace * invs;

  // ---- init: Y0 = G/s + eps*I (single bf16), Z0 = I ----
#pragma unroll
  for (int t = 0; t < 8; ++t) {
    int idx4 = tid + 512 * t;
    int flat = idx4 * 4, i = flat >> 7, j0 = flat & 127;
    s16x4 vh;
#pragma unroll
    for (int e = 0; e < 4; ++e) {
      float x = ((const float*)&gs[t])[e] * invs + ((i == j0 + e) ? eps : 0.f);
      vh[e] = (short)f2bf(x);
    }
    *(s16x4*)(Yb + swz_idx(i, j0)) = vh;
  }
  for (int grp = tid; grp < DIM * 16; grp += 512) {
    int i = grp >> 4, g = grp & 15;
    s16x8 v = (s16x8)0;
    if ((i >> 3) == g) v[i & 7] = (short)0x3F80;   // 1.0 bf16
    *(s16x8*)(Zb + i * 128 + ((g ^ (i & 15)) << 3)) = v;
  }
  __syncthreads();

  for (int it = 0; it < NITER; ++it) {
    const float kA = NS_C1[it];
    const float kB = NS_C2[it];

    // --- (a) W = Z*Y ---
    f32x4 acc[4][2];
#pragma unroll
    for (int r = 0; r < 4; ++r)
#pragma unroll
      for (int c2 = 0; c2 < 2; ++c2) acc[r][c2] = (f32x4)0.f;
#pragma unroll
    for (int ks = 0; ks < 4; ++ks) {
      s16x8 a[4], b[2];
#pragma unroll
      for (int r = 0; r < 4; ++r) a[r] = load_frag(Zb, (4 * wr + r) * 16, ks, lane);
#pragma unroll
      for (int c2 = 0; c2 < 2; ++c2) b[c2] = load_frag(Yb, (2 * wc + c2) * 16, ks, lane);
#pragma unroll
      for (int r = 0; r < 4; ++r)
#pragma unroll
        for (int c2 = 0; c2 < 2; ++c2)
          acc[r][c2] = __builtin_amdgcn_mfma_f32_16x16x32_bf16(a[r], b[c2], acc[r][c2], 0, 0, 0);
    }
    // --- (b) M = kA*I - kB*W, clamp, hi/lo split, transposed store ---
#pragma unroll
    for (int r = 0; r < 4; ++r) {
      int ibase = (4 * wr + r) * 16 + quad * 4;
      int cg    = ibase >> 3;
#pragma unroll
      for (int c2 = 0; c2 < 2; ++c2) {
        int jg  = (2 * wc + c2) * 16 + (lane & 15);
        int idx = jg * 128 + ((cg ^ (jg & 15)) << 3) + (ibase & 7);
        s16x4 vh, vl;
#pragma unroll
        for (int e = 0; e < 4; ++e) {
          float mv = -kB * acc[r][c2][e] + ((ibase + e == jg) ? kA : 0.f);
          mv = fminf(fmaxf(mv, -4.f), 4.f);
          unsigned short hh = f2bf(mv);
          vh[e] = (short)hh;
          vl[e] = (short)f2bf(mv - bf2f(hh));
        }
        *(s16x4*)(Mh + idx) = vh;
        *(s16x4*)(Ml + idx) = vl;
      }
    }
    __syncthreads();

    // --- (c) Y' = M*Y, Z' = M*Z (M = shared split-A; iterates commute) ---
    f32x4 ay[4][2], az[4][2];
#pragma unroll
    for (int r = 0; r < 4; ++r)
#pragma unroll
      for (int c2 = 0; c2 < 2; ++c2) { ay[r][c2] = (f32x4)0.f; az[r][c2] = (f32x4)0.f; }
#pragma unroll
    for (int ks = 0; ks < 4; ++ks) {
      s16x8 aMh[4], aMl[4], bY[2], bZ[2];
#pragma unroll
      for (int r = 0; r < 4; ++r) {
        int rb = (4 * wr + r) * 16;
        aMh[r] = load_frag(Mh, rb, ks, lane);
        aMl[r] = load_frag(Ml, rb, ks, lane);
      }
#pragma unroll
      for (int c2 = 0; c2 < 2; ++c2) {
        int cb = (2 * wc + c2) * 16;
        bY[c2] = load_frag(Yb, cb, ks, lane);
        bZ[c2] = load_frag(Zb, cb, ks, lane);
      }
#pragma unroll
      for (int r = 0; r < 4; ++r)
#pragma unroll
        for (int c2 = 0; c2 < 2; ++c2) {
          ay[r][c2] = __builtin_amdgcn_mfma_f32_16x16x32_bf16(aMh[r], bY[c2], ay[r][c2], 0, 0, 0);
          ay[r][c2] = __builtin_amdgcn_mfma_f32_16x16x32_bf16(aMl[r], bY[c2], ay[r][c2], 0, 0, 0);
          az[r][c2] = __builtin_amdgcn_mfma_f32_16x16x32_bf16(aMh[r], bZ[c2], az[r][c2], 0, 0, 0);
          az[r][c2] = __builtin_amdgcn_mfma_f32_16x16x32_bf16(aMl[r], bZ[c2], az[r][c2], 0, 0, 0);
        }
    }
    __syncthreads();

    // --- (d) store Y' (single), Z' (single), transposed ---
#pragma unroll
    for (int r = 0; r < 4; ++r) {
      int ibase = (4 * wr + r) * 16 + quad * 4;
      int cg    = ibase >> 3;
#pragma unroll
      for (int c2 = 0; c2 < 2; ++c2) {
        int jg  = (2 * wc + c2) * 16 + (lane & 15);
        int idx = jg * 128 + ((cg ^ (jg & 15)) << 3) + (ibase & 7);
        s16x4 vy, vz;
#pragma unroll
        for (int e = 0; e < 4; ++e) {
          vy[e] = (short)f2bf(ay[r][c2][e]);
          vz[e] = (short)f2bf(az[r][c2][e]);
        }
        *(s16x4*)(Yb + idx) = vy;
        *(s16x4*)(Zb + idx) = vz;
      }
    }
    __syncthreads();
  }

  // ---- traces: tr(GZ) (fp32 G anchor), tr(Z), tr(Z^3) ----
  float t_gz = 0.f, t_z = 0.f, t_z3 = 0.f;
#pragma unroll
  for (int t = 0; t < 8; ++t) {
    int idx4 = tid + 512 * t;
    int flat = idx4 * 4, i = flat >> 7, j0 = flat & 127;
    s16x4 zv = *(const s16x4*)(Zb + swz_idx(i, j0));
#pragma unroll
    for (int e = 0; e < 4; ++e) t_gz += ((const float*)&gs[t])[e] * bf2f((unsigned short)zv[e]);
  }
  if (tid < DIM) t_z = bf2f((unsigned short)Zb[swz_idx(tid, tid)]);

  {  // U = Z*Z tile-wise; tr(Z^3) = sum U_ij * Z_ji
    f32x4 u[4][2];
#pragma unroll
    for (int r = 0; r < 4; ++r)
#pragma unroll
      for (int c2 = 0; c2 < 2; ++c2) u[r][c2] = (f32x4)0.f;
#pragma unroll
    for (int ks = 0; ks < 4; ++ks) {
      s16x8 a[4], b[2];
#pragma unroll
      for (int r = 0; r < 4; ++r) a[r] = load_frag(Zb, (4 * wr + r) * 16, ks, lane);
#pragma unroll
      for (int c2 = 0; c2 < 2; ++c2) b[c2] = load_frag(Zb, (2 * wc + c2) * 16, ks, lane);
#pragma unroll
      for (int r = 0; r < 4; ++r)
#pragma unroll
        for (int c2 = 0; c2 < 2; ++c2)
          u[r][c2] = __builtin_amdgcn_mfma_f32_16x16x32_bf16(a[r], b[c2], u[r][c2], 0, 0, 0);
    }
#pragma unroll
    for (int r = 0; r < 4; ++r) {
      int ibase = (4 * wr + r) * 16 + quad * 4;
      int cg    = ibase >> 3;
#pragma unroll
      for (int c2 = 0; c2 < 2; ++c2) {
        int jg  = (2 * wc + c2) * 16 + (lane & 15);
        int idx = jg * 128 + ((cg ^ (jg & 15)) << 3) + (ibase & 7);
        s16x4 zt = *(const s16x4*)(Zb + idx);
#pragma unroll
        for (int e = 0; e < 4; ++e) t_z3 += u[r][c2][e] * bf2f((unsigned short)zt[e]);
      }
    }
  }

  for (int off = 32; off > 0; off >>= 1) {
    t_gz += __shfl_down(t_gz, off, 64);
    t_z  += __shfl_down(t_z,  off, 64);
    t_z3 += __shfl_down(t_z3, off, 64);
  }
  __syncthreads();
  float* red = (float*)Mh;             // Mh dead after last iter
  if (lane == 0) { red[wv] = t_gz; red[8 + wv] = t_z; red[16 + wv] = t_z3; }
  __syncthreads();

  float nuc_own = 0.f;
  if (tid == 0) {
    float gz = 0.f, z1 = 0.f, z3 = 0.f;
#pragma unroll
    for (int w = 0; w < 8; ++w) { gz += red[w]; z1 += red[8 + w]; z3 += red[16 + w]; }
    float trsq = gz * invs + 0.5f * eps * z1 - 0.125f * eps * eps * z3;
    nuc_own = sqrtf(s) * trsq;
    nuc[bid] = nuc_own;
  }

  if (bid < NCLS) {
    if (tid == 0) flag_set(&nflag[bid]);
    return;
  }

  // ======== block 64: final combine (parallel poll, one flag/lane) ========
  if (tid < NCLS) flag_wait(&nflag[tid]);
  __syncthreads();

  float ce2 = cepart[tid];                       // 512 entries, 512 threads
  float vmx = (tid < NCLS) ? fmaxf(nuc[tid], DELTA_) : 0.f;
  for (int off = 32; off > 0; off >>= 1) {
    vmx += __shfl_down(vmx, off, 64);
    ce2 += __shfl_down(ce2, off, 64);
  }
  if (lane == 0) { red[wv] = vmx; red[8 + wv] = ce2; }
  __syncthreads();
  if (tid == 0) {
    float vs = 0.f, cs = 0.f;
#pragma unroll
    for (int w = 0; w < 8; ++w) { vs += red[w]; cs += red[8 + w]; }
    float ole = (vs - nuc_own) * (LAMBDA_ / (float)N_ROWS);
    out[0] = ole + cs / (float)N_ROWS;
  }
}

extern "C" void kernel_launch(void* const* d_in, const int* in_sizes, int n_in,
                              void* d_out, int out_size, void* d_ws, size_t ws_size,
                              hipStream_t stream) {
  const float* logits = (const float*)d_in[0];   // out  [8192,64]
  const float* feat   = (const float*)d_in[1];   // feat [8192,128]
  const int*   yp     = (const int*)d_in[2];     // y    [8192]

  float* G      = (float*)d_ws;                  // 64 class mats + Gall (idx 64)
  float* nuc    = G + (size_t)NMAT * DIM * DIM;  // 65 (+pad)
  float* cepart = nuc + NMAT + 3;                // 512
  int*   gallf  = (int*)(cepart + 512);          // 16
  int*   nflag  = gallf + 16;                    // 64

  ole_gram_ce<<<NCLS + 128, 256, 0, stream>>>(feat, yp, logits, G, cepart);
  ole_ns<<<NMAT + 16, 512, 0, stream>>>(G, G, nuc, cepart, gallf, nflag,
                                        (float*)d_out);
}

// Round 14
// 135.983 us; speedup vs baseline: 3.5306x; 1.0411x over previous
//
#include <hip/hip_runtime.h>
#include <math.h>

// OLE loss on MI355X — 2 dispatches (R12 structure).
// ||X_c||* = trace(sqrt(G_c)), G_c = X_c^T X_c (128x128).
// K1: blocks 0..63 per-class Gram -> G_c; blocks 64..191 CE -> cepart.
// K2: blocks 65..80 Gall slices -> magic flag; blocks 0..63 NS(G_c) ->
//     nuc + magic flag; block 64 parallel-waits gallf (one flag/lane),
//     NS(Gall), parallel-waits nflag, final combine.
// R14: NITER 8->7 — scalar trajectory of the ladder map over the full
// guaranteed spectrum [eps_norm=1.6e-3, 1] shows |w-1|<=1.5e-3 by k5 and
// <=1e-5 by k6; k7 was polishing converged modes.  Y single bf16; M hi/lo
// split (that split is the one that matters — R4 failure).  Lessons:
// R8 grid.sync ~50us/barrier; R11 serial flag polls -> one flag per lane.

#define N_ROWS 8192
#define DIM    128
#define NCLS   64
#define NMAT   65
#define NITER  7
#define EPSN   2e-4f
#define LAMBDA_ 0.25f
#define DELTA_  1.0f
#define MAGIC  0x13579BDF   // != 0xAAAAAAAA poison, != 0

typedef __attribute__((ext_vector_type(8))) short s16x8;  // 8 bf16 = 4 VGPR
typedef __attribute__((ext_vector_type(4))) short s16x4;  // 4 bf16
typedef __attribute__((ext_vector_type(4))) float f32x4;

// Scaled-NS ladder: M_k = C1[k]*I - C2[k]*W, C1 = 1.5*sqrt(t), C2 = 0.5*t^1.5.
// t = [2.9, 2.758, 2.13, 1.868, 1.264, 1, 1]; u = t*w, w' = u(1.5-u/2)^2
// stays in [0,1] for u in (0,3) -> sign-safe; final t=1 steps polish w->1.
static __device__ const float NS_C1[NITER] =
  {2.554408f, 2.491084f, 2.189178f, 2.050122f, 1.686417f, 1.5f, 1.5f};
static __device__ const float NS_C2[NITER] =
  {2.469261f, 2.290137f, 1.554316f, 1.276543f, 0.710544f, 0.5f, 0.5f};

__device__ __forceinline__ unsigned short f2bf(float f) {   // RNE
  unsigned u = __float_as_uint(f);
  u = (u + 0x7FFFu + ((u >> 16) & 1u)) >> 16;
  return (unsigned short)u;
}
__device__ __forceinline__ float bf2f(unsigned short h) {
  return __uint_as_float(((unsigned)h) << 16);
}

// bf16 LDS: element (i,j) at short-index i*128 + (((j>>3)^(i&15))<<3) + (j&7)
__device__ __forceinline__ int swz_idx(int i, int j) {
  return i * 128 + (((j >> 3) ^ (i & 15)) << 3) + (j & 7);
}

__device__ __forceinline__ s16x8 load_frag(const short* buf, int row0,
                                           int kstep, int lane) {
  int m  = row0 + (lane & 15);
  int kg = kstep * 4 + (lane >> 4);
  return *(const s16x8*)(buf + m * 128 + ((kg ^ (m & 15)) << 3));
}

__device__ __forceinline__ void flag_set(int* p) {
  __threadfence();
  __hip_atomic_store(p, MAGIC, __ATOMIC_RELEASE, __HIP_MEMORY_SCOPE_AGENT);
}
__device__ __forceinline__ void flag_wait(const int* p) {
  while (__hip_atomic_load(p, __ATOMIC_ACQUIRE, __HIP_MEMORY_SCOPE_AGENT) != MAGIC)
    __builtin_amdgcn_s_sleep(8);
}

// ---------------------------------------------------------------------------
// Kernel 1: blocks 0..63 = per-class Gram; blocks 64..191 = cross-entropy.
// (R7-proven; zero inter-block communication.)
// ---------------------------------------------------------------------------
__global__ __launch_bounds__(256) void ole_gram_ce(const float* __restrict__ feat,
                                                   const int* __restrict__ y,
                                                   const float* __restrict__ logits,
                                                   float* __restrict__ G,
                                                   float* __restrict__ cepart) {
  __shared__ int   list[N_ROWS];
  __shared__ int   cnt;
  __shared__ float xs[8][DIM];

  const int tid = threadIdx.x;

  if (blockIdx.x >= NCLS) {
    // ---------------- CE path (128 blocks, 512 waves) ----------------
    const int blk    = blockIdx.x - NCLS;
    const int gwave  = blk * 4 + (tid >> 6);
    const int lane   = tid & 63;

    float acc = 0.f;
    for (int row = gwave; row < N_ROWS; row += 512) {
      float v = logits[row * NCLS + lane];
      float mx = v;
      for (int off = 32; off > 0; off >>= 1) mx = fmaxf(mx, __shfl_xor(mx, off, 64));
      float e = expf(v - mx);
      for (int off = 32; off > 0; off >>= 1) e += __shfl_xor(e, off, 64);
      if (lane == 0) {
        int t = y[row];
        acc += (mx + logf(e)) - logits[row * NCLS + t];
      }
    }
    if (lane == 0) cepart[gwave] = acc;
    return;
  }

  // ---------------- gram path (64 blocks) ----------------
  const int c  = blockIdx.x;
  const int ti = tid >> 4, tj = tid & 15;
  const int i0 = ti * 8,  j0 = tj * 8;

  if (tid == 0) cnt = 0;
  __syncthreads();
  const int4* y4 = (const int4*)y;
#pragma unroll
  for (int t = 0; t < 8; ++t) {
    int g4 = tid + 256 * t;
    int4 v = y4[g4];
    int r0 = g4 * 4;
    if (v.x == c) list[atomicAdd(&cnt, 1)] = r0;
    if (v.y == c) list[atomicAdd(&cnt, 1)] = r0 + 1;
    if (v.z == c) list[atomicAdd(&cnt, 1)] = r0 + 2;
    if (v.w == c) list[atomicAdd(&cnt, 1)] = r0 + 3;
  }
  __syncthreads();
  const int n = cnt;

  float acc[8][8];
#pragma unroll
  for (int a = 0; a < 8; ++a)
#pragma unroll
    for (int b = 0; b < 8; ++b) acc[a][b] = 0.f;

  const int ldrow = tid >> 5;
  const int ldcol = (tid & 31) * 4;

  for (int base = 0; base < n; base += 8) {
    __syncthreads();
    int li = base + ldrow;
    float4 v = make_float4(0.f, 0.f, 0.f, 0.f);
    if (li < n) v = *(const float4*)(feat + (size_t)list[li] * DIM + ldcol);
    *(float4*)(&xs[ldrow][ldcol]) = v;
    __syncthreads();
#pragma unroll
    for (int rw = 0; rw < 8; ++rw) {
      float xi[8], xj[8];
#pragma unroll
      for (int a = 0; a < 8; ++a) xi[a] = xs[rw][i0 + a];
#pragma unroll
      for (int b = 0; b < 8; ++b) xj[b] = xs[rw][j0 + b];
#pragma unroll
      for (int a = 0; a < 8; ++a)
#pragma unroll
        for (int b = 0; b < 8; ++b) acc[a][b] = fmaf(xi[a], xj[b], acc[a][b]);
    }
  }

  float* Gc = G + (size_t)c * DIM * DIM;
#pragma unroll
  for (int a = 0; a < 8; ++a)
#pragma unroll
    for (int b = 0; b < 8; ++b)
      Gc[(i0 + a) * DIM + (j0 + b)] = acc[a][b];
}

// ---------------------------------------------------------------------------
// Kernel 2: 81 blocks x 512.
//  blocks 65..80: Gall slice (reads kernel-1 G, waits on nothing) -> gallf
//  blocks 0..63:  NS(G_c) -> nuc[c] -> nflag[c]
//  block 64:      parallel-wait gallf -> NS(Gall) -> parallel-wait nflag
//                 -> final combine -> out
// LDS: Yb (single), Mh, Ml, Zb = 4 x 32 KB = 128 KiB.
// ---------------------------------------------------------------------------
__global__ __launch_bounds__(512, 1) void ole_ns(const float* __restrict__ G,
                                                 float* __restrict__ Gmut,
                                                 float* __restrict__ nuc,
                                                 const float* __restrict__ cepart,
                                                 int* __restrict__ gallf,
                                                 int* __restrict__ nflag,
                                                 float* __restrict__ out) {
  __shared__ short Yb[DIM * DIM];
  __shared__ short Mh[DIM * DIM];
  __shared__ short Ml[DIM * DIM];
  __shared__ short Zb[DIM * DIM];

  const int bid  = blockIdx.x;
  const int tid  = threadIdx.x;
  const int lane = tid & 63;
  const int quad = lane >> 4;
  const int wv   = tid >> 6;    // 0..7

  // ---------------- Gall-builder blocks (65..80) ----------------
  if (bid > NCLS) {
    const int gb = bid - NCLS - 1;        // 0..15
    if (tid < 256) {
      int idx4 = gb * 256 + tid;          // 16 x 256 = 4096 float4s
      const float4* G4 = (const float4*)G;
      float4 s = make_float4(0.f, 0.f, 0.f, 0.f);
#pragma unroll 8
      for (int c = 0; c < NCLS; ++c) {
        float4 v = G4[(size_t)c * (DIM * DIM / 4) + idx4];
        s.x += v.x; s.y += v.y; s.z += v.z; s.w += v.w;
      }
      ((float4*)Gmut)[(size_t)NCLS * (DIM * DIM / 4) + idx4] = s;
    }
    __syncthreads();
    if (tid == 0) flag_set(&gallf[gb]);
    return;
  }

  // ---------------- block 64: wait for Gall (parallel poll) ----------------
  if (bid == NCLS) {
    if (tid < 16) flag_wait(&gallf[tid]);   // one flag per lane
    __syncthreads();
  }

  const int wr = wv >> 2;     // 0..1 -> tile-rows 4*wr..4*wr+3
  const int wc = wv & 3;      // 0..3 -> tile-cols 2*wc..2*wc+1

  const float4* Gm4 = (const float4*)(G + (size_t)bid * DIM * DIM);

  // ---- load G (8 float4/thread), in-block trace + fro2 ----
  float4 gs[8];
  float tpart = 0.f, fpart = 0.f;
#pragma unroll
  for (int t = 0; t < 8; ++t) {
    int idx4 = tid + 512 * t;
    float4 v = Gm4[idx4];
    gs[t] = v;
    fpart += v.x * v.x + v.y * v.y + v.z * v.z + v.w * v.w;
    int flat = idx4 * 4, i = flat >> 7, j0 = flat & 127;
    if (j0 <= i && i < j0 + 4) tpart += ((const float*)&v)[i - j0];
  }
  for (int off = 32; off > 0; off >>= 1) {
    tpart += __shfl_down(tpart, off, 64);
    fpart += __shfl_down(fpart, off, 64);
  }
  float* redf = (float*)Zb;           // Zb not yet initialized
  if (lane == 0) { redf[wv] = tpart; redf[8 + wv] = fpart; }
  __syncthreads();
  float trace = 0.f, fro2 = 0.f;
#pragma unroll
  for (int w = 0; w < 8; ++w) { trace += redf[w]; fro2 += redf[8 + w]; }
  __syncthreads();                    // redf reads done -> Zb reusable

  float s = sqrtf(fro2);
  if (s < 1e-12f) s = 1.f;
  const float invs = 1.f / s;
  const float eps  = EPSN * trace * invs;

  // ---- init: Y0 = G/s + eps*I (single bf16), Z0 = I ----
#pragma unroll
  for (int t = 0; t < 8; ++t) {
    int idx4 = tid + 512 * t;
    int flat = idx4 * 4, i = flat >> 7, j0 = flat & 127;
    s16x4 vh;
#pragma unroll
    for (int e = 0; e < 4; ++e) {
      float x = ((const float*)&gs[t])[e] * invs + ((i == j0 + e) ? eps : 0.f);
      vh[e] = (short)f2bf(x);
    }
    *(s16x4*)(Yb + swz_idx(i, j0)) = vh;
  }
  for (int grp = tid; grp < DIM * 16; grp += 512) {
    int i = grp >> 4, g = grp & 15;
    s16x8 v = (s16x8)0;
    if ((i >> 3) == g) v[i & 7] = (short)0x3F80;   // 1.0 bf16
    *(s16x8*)(Zb + i * 128 + ((g ^ (i & 15)) << 3)) = v;
  }
  __syncthreads();

  for (int it = 0; it < NITER; ++it) {
    const float kA = NS_C1[it];
    const float kB = NS_C2[it];

    // --- (a) W = Z*Y ---
    f32x4 acc[4][2];
#pragma unroll
    for (int r = 0; r < 4; ++r)
#pragma unroll
      for (int c2 = 0; c2 < 2; ++c2) acc[r][c2] = (f32x4)0.f;
#pragma unroll
    for (int ks = 0; ks < 4; ++ks) {
      s16x8 a[4], b[2];
#pragma unroll
      for (int r = 0; r < 4; ++r) a[r] = load_frag(Zb, (4 * wr + r) * 16, ks, lane);
#pragma unroll
      for (int c2 = 0; c2 < 2; ++c2) b[c2] = load_frag(Yb, (2 * wc + c2) * 16, ks, lane);
#pragma unroll
      for (int r = 0; r < 4; ++r)
#pragma unroll
        for (int c2 = 0; c2 < 2; ++c2)
          acc[r][c2] = __builtin_amdgcn_mfma_f32_16x16x32_bf16(a[r], b[c2], acc[r][c2], 0, 0, 0);
    }
    // --- (b) M = kA*I - kB*W, clamp, hi/lo split, transposed store ---
#pragma unroll
    for (int r = 0; r < 4; ++r) {
      int ibase = (4 * wr + r) * 16 + quad * 4;
      int cg    = ibase >> 3;
#pragma unroll
      for (int c2 = 0; c2 < 2; ++c2) {
        int jg  = (2 * wc + c2) * 16 + (lane & 15);
        int idx = jg * 128 + ((cg ^ (jg & 15)) << 3) + (ibase & 7);
        s16x4 vh, vl;
#pragma unroll
        for (int e = 0; e < 4; ++e) {
          float mv = -kB * acc[r][c2][e] + ((ibase + e == jg) ? kA : 0.f);
          mv = fminf(fmaxf(mv, -4.f), 4.f);
          unsigned short hh = f2bf(mv);
          vh[e] = (short)hh;
          vl[e] = (short)f2bf(mv - bf2f(hh));
        }
        *(s16x4*)(Mh + idx) = vh;
        *(s16x4*)(Ml + idx) = vl;
      }
    }
    __syncthreads();

    // --- (c) Y' = M*Y, Z' = M*Z (M = shared split-A; iterates commute) ---
    f32x4 ay[4][2], az[4][2];
#pragma unroll
    for (int r = 0; r < 4; ++r)
#pragma unroll
      for (int c2 = 0; c2 < 2; ++c2) { ay[r][c2] = (f32x4)0.f; az[r][c2] = (f32x4)0.f; }
#pragma unroll
    for (int ks = 0; ks < 4; ++ks) {
      s16x8 aMh[4], aMl[4], bY[2], bZ[2];
#pragma unroll
      for (int r = 0; r < 4; ++r) {
        int rb = (4 * wr + r) * 16;
        aMh[r] = load_frag(Mh, rb, ks, lane);
        aMl[r] = load_frag(Ml, rb, ks, lane);
      }
#pragma unroll
      for (int c2 = 0; c2 < 2; ++c2) {
        int cb = (2 * wc + c2) * 16;
        bY[c2] = load_frag(Yb, cb, ks, lane);
        bZ[c2] = load_frag(Zb, cb, ks, lane);
      }
#pragma unroll
      for (int r = 0; r < 4; ++r)
#pragma unroll
        for (int c2 = 0; c2 < 2; ++c2) {
          ay[r][c2] = __builtin_amdgcn_mfma_f32_16x16x32_bf16(aMh[r], bY[c2], ay[r][c2], 0, 0, 0);
          ay[r][c2] = __builtin_amdgcn_mfma_f32_16x16x32_bf16(aMl[r], bY[c2], ay[r][c2], 0, 0, 0);
          az[r][c2] = __builtin_amdgcn_mfma_f32_16x16x32_bf16(aMh[r], bZ[c2], az[r][c2], 0, 0, 0);
          az[r][c2] = __builtin_amdgcn_mfma_f32_16x16x32_bf16(aMl[r], bZ[c2], az[r][c2], 0, 0, 0);
        }
    }
    __syncthreads();

    // --- (d) store Y' (single), Z' (single), transposed ---
#pragma unroll
    for (int r = 0; r < 4; ++r) {
      int ibase = (4 * wr + r) * 16 + quad * 4;
      int cg    = ibase >> 3;
#pragma unroll
      for (int c2 = 0; c2 < 2; ++c2) {
        int jg  = (2 * wc + c2) * 16 + (lane & 15);
        int idx = jg * 128 + ((cg ^ (jg & 15)) << 3) + (ibase & 7);
        s16x4 vy, vz;
#pragma unroll
        for (int e = 0; e < 4; ++e) {
          vy[e] = (short)f2bf(ay[r][c2][e]);
          vz[e] = (short)f2bf(az[r][c2][e]);
        }
        *(s16x4*)(Yb + idx) = vy;
        *(s16x4*)(Zb + idx) = vz;
      }
    }
    __syncthreads();
  }

  // ---- traces: tr(GZ) (fp32 G anchor), tr(Z), tr(Z^3) ----
  float t_gz = 0.f, t_z = 0.f, t_z3 = 0.f;
#pragma unroll
  for (int t = 0; t < 8; ++t) {
    int idx4 = tid + 512 * t;
    int flat = idx4 * 4, i = flat >> 7, j0 = flat & 127;
    s16x4 zv = *(const s16x4*)(Zb + swz_idx(i, j0));
#pragma unroll
    for (int e = 0; e < 4; ++e) t_gz += ((const float*)&gs[t])[e] * bf2f((unsigned short)zv[e]);
  }
  if (tid < DIM) t_z = bf2f((unsigned short)Zb[swz_idx(tid, tid)]);

  {  // U = Z*Z tile-wise; tr(Z^3) = sum U_ij * Z_ji
    f32x4 u[4][2];
#pragma unroll
    for (int r = 0; r < 4; ++r)
#pragma unroll
      for (int c2 = 0; c2 < 2; ++c2) u[r][c2] = (f32x4)0.f;
#pragma unroll
    for (int ks = 0; ks < 4; ++ks) {
      s16x8 a[4], b[2];
#pragma unroll
      for (int r = 0; r < 4; ++r) a[r] = load_frag(Zb, (4 * wr + r) * 16, ks, lane);
#pragma unroll
      for (int c2 = 0; c2 < 2; ++c2) b[c2] = load_frag(Zb, (2 * wc + c2) * 16, ks, lane);
#pragma unroll
      for (int r = 0; r < 4; ++r)
#pragma unroll
        for (int c2 = 0; c2 < 2; ++c2)
          u[r][c2] = __builtin_amdgcn_mfma_f32_16x16x32_bf16(a[r], b[c2], u[r][c2], 0, 0, 0);
    }
#pragma unroll
    for (int r = 0; r < 4; ++r) {
      int ibase = (4 * wr + r) * 16 + quad * 4;
      int cg    = ibase >> 3;
#pragma unroll
      for (int c2 = 0; c2 < 2; ++c2) {
        int jg  = (2 * wc + c2) * 16 + (lane & 15);
        int idx = jg * 128 + ((cg ^ (jg & 15)) << 3) + (ibase & 7);
        s16x4 zt = *(const s16x4*)(Zb + idx);
#pragma unroll
        for (int e = 0; e < 4; ++e) t_z3 += u[r][c2][e] * bf2f((unsigned short)zt[e]);
      }
    }
  }

  for (int off = 32; off > 0; off >>= 1) {
    t_gz += __shfl_down(t_gz, off, 64);
    t_z  += __shfl_down(t_z,  off, 64);
    t_z3 += __shfl_down(t_z3, off, 64);
  }
  __syncthreads();
  float* red = (float*)Mh;             // Mh dead after last iter
  if (lane == 0) { red[wv] = t_gz; red[8 + wv] = t_z; red[16 + wv] = t_z3; }
  __syncthreads();

  float nuc_own = 0.f;
  if (tid == 0) {
    float gz = 0.f, z1 = 0.f, z3 = 0.f;
#pragma unroll
    for (int w = 0; w < 8; ++w) { gz += red[w]; z1 += red[8 + w]; z3 += red[16 + w]; }
    float trsq = gz * invs + 0.5f * eps * z1 - 0.125f * eps * eps * z3;
    nuc_own = sqrtf(s) * trsq;
    nuc[bid] = nuc_own;
  }

  if (bid < NCLS) {
    if (tid == 0) flag_set(&nflag[bid]);
    return;
  }

  // ======== block 64: final combine (parallel poll, one flag/lane) ========
  if (tid < NCLS) flag_wait(&nflag[tid]);
  __syncthreads();

  float ce2 = cepart[tid];                       // 512 entries, 512 threads
  float vmx = (tid < NCLS) ? fmaxf(nuc[tid], DELTA_) : 0.f;
  for (int off = 32; off > 0; off >>= 1) {
    vmx += __shfl_down(vmx, off, 64);
    ce2 += __shfl_down(ce2, off, 64);
  }
  if (lane == 0) { red[wv] = vmx; red[8 + wv] = ce2; }
  __syncthreads();
  if (tid == 0) {
    float vs = 0.f, cs = 0.f;
#pragma unroll
    for (int w = 0; w < 8; ++w) { vs += red[w]; cs += red[8 + w]; }
    float ole = (vs - nuc_own) * (LAMBDA_ / (float)N_ROWS);
    out[0] = ole + cs / (float)N_ROWS;
  }
}

extern "C" void kernel_launch(void* const* d_in, const int* in_sizes, int n_in,
                              void* d_out, int out_size, void* d_ws, size_t ws_size,
                              hipStream_t stream) {
  const float* logits = (const float*)d_in[0];   // out  [8192,64]
  const float* feat   = (const float*)d_in[1];   // feat [8192,128]
  const int*   yp     = (const int*)d_in[2];     // y    [8192]

  float* G      = (float*)d_ws;                  // 64 class mats + Gall (idx 64)
  float* nuc    = G + (size_t)NMAT * DIM * DIM;  // 65 (+pad)
  float* cepart = nuc + NMAT + 3;                // 512
  int*   gallf  = (int*)(cepart + 512);          // 16
  int*   nflag  = gallf + 16;                    // 64

  ole_gram_ce<<<NCLS + 128, 256, 0, stream>>>(feat, yp, logits, G, cepart);
  ole_ns<<<NMAT + 16, 512, 0, stream>>>(G, G, nuc, cepart, gallf, nflag,
                                        (float*)d_out);
}